// Round 13
// baseline (121.517 us; speedup 1.0000x reference)
//
#include <hip/hip_runtime.h>

#define NBATCH 4096
#define OUT2 (NBATCH * 64)

typedef _Float16 f16;
typedef __attribute__((ext_vector_type(8))) _Float16 f16x8;
typedef __attribute__((ext_vector_type(4))) _Float16 f16x4;
typedef __attribute__((ext_vector_type(4))) float f32x4;

__device__ __forceinline__ float lrelu(float x) { return x > 0.0f ? x : 0.2f * x; }
__device__ __forceinline__ float elu1(float x)  { return x > 0.0f ? x : __expf(x) - 1.0f; }

// ---------------- prep ----------------
// ws: [0,32768)      w2b  f16 MFMA B-frags: w2b[((F2T*4+kf)*64+ln)*8+j] = W2[kf*32+(ln>>4)*8+j][F2T*16+(ln&15)]
//     [32768,32792)  w1a  f32[6] = {W1^T@a1[:128] (3), W1^T@a1[128:] (3)}
//     [32800,36896)  w2ab f16 B-frags of [W2@a2[:128] | W2@a2[128:]] (2 cols)
__global__ void prep(const float* __restrict__ W2, const float* __restrict__ W1,
                     const float* __restrict__ a1, const float* __restrict__ a2,
                     f16* __restrict__ w2b, float* __restrict__ w1a, f16* __restrict__ w2ab) {
    const int flat = blockIdx.x * 256 + threadIdx.x;   // 0..16383
    const int slot = flat >> 3, j = flat & 7;
    const int F2T = slot >> 8, kf = (slot >> 6) & 3, ln = slot & 63;
    const int lq = ln >> 4, lr = ln & 15;
    w2b[flat] = (f16)W2[(kf * 32 + lq * 8 + j) * 128 + F2T * 16 + lr];
    if (flat < 2048) {
        const int ks = flat >> 9, ln2 = (flat >> 3) & 63, jj = flat & 7;
        const int k = ks * 32 + ((ln2 >> 4) & 3) * 8 + jj;
        const int n = ln2 & 15;
        float v = 0.f;
        if (n < 2) {
            const float* av = a2 + n * 128;
            for (int f2 = 0; f2 < 128; ++f2) v = fmaf(W2[k * 128 + f2], av[f2], v);
        }
        w2ab[flat] = (f16)v;
    }
    if (flat >= 16381) {   // last 3 threads: w1a
        const int c = flat - 16381;
        float si = 0.f, sj = 0.f;
        for (int f = 0; f < 128; ++f) {
            const float w = W1[c * 128 + f];
            si = fmaf(w, a1[f], si);
            sj = fmaf(w, a1[128 + f], sj);
        }
        w1a[c] = si; w1a[3 + c] = sj;
    }
}

// sMain (16 KB): dual-role.
//  - layer-1 bounce: h1[node n][feat_local fl] : n*64 + (((fl>>3)^(n&7))<<3) + (fl&7)  (8 KB used)
//  - layer-2 Wh2 FULL: [feat f 0..127][node n] : f*64 + (((n>>3)^(f&7))<<3) + (n&7)    (16 KB)
__global__ __launch_bounds__(64, 3)   // phases strictly sequential: F peak=hf(64)+bw2(32),
                                      // E1 peak=bp(32)+transients — both < cap, no spill
void gat_kernel(const float* __restrict__ users,
                const float* __restrict__ W1,
                const f16* __restrict__ w2b,
                const float* __restrict__ w1a,
                const f16* __restrict__ w2ab,
                const float* __restrict__ mw1,
                const float* __restrict__ mb1,
                const float* __restrict__ mw2,
                const float* __restrict__ mb2,
                float* __restrict__ out)
{
    const int b = blockIdx.x;
    const int lane = threadIdx.x;      // one wave per block, one batch per wave
    const int lr = lane & 15;
    const int lq = lane >> 4;

    __shared__ __align__(16) char smem[17536];
    f16*   sMain = (f16*)smem;                  // 16384 B
    float* sSi   = (float*)(smem + 16384);      // 64 f32
    float* sSj   = (float*)(smem + 16640);      // 64 f32
    float* sPool = (float*)(smem + 16896);      // 128 f32
    float* sHid  = (float*)(smem + 17408);      // 32 f32

    // ---- scores layer 1: rank-3 (exact fp32) ----
    {
        const float* u = users + b * 192;
        const float x = u[lane * 3], y = u[lane * 3 + 1], z = u[lane * 3 + 2];
        sSi[lane] = fmaf(x, w1a[0], fmaf(y, w1a[1], z * w1a[2]));
        sSj[lane] = fmaf(x, w1a[3], fmaf(y, w1a[4], z * w1a[5]));
    }
    __syncthreads();

    // ---- softmax-1 fragments (no max-shift: scores are O(1)) ----
    f16x8 ap[4][2];     // P1 as B-frags: B[k=j][n=i_local], i = mt*16+lr
    float inv1[4];
    {
        float sjv[16];
        *(float4*)&sjv[0]  = *(const float4*)&sSj[lq * 8];
        *(float4*)&sjv[4]  = *(const float4*)&sSj[lq * 8 + 4];
        *(float4*)&sjv[8]  = *(const float4*)&sSj[32 + lq * 8];
        *(float4*)&sjv[12] = *(const float4*)&sSj[32 + lq * 8 + 4];
        #pragma unroll
        for (int mt = 0; mt < 4; ++mt) {
            const float si = sSi[mt * 16 + lr];
            float lsum = 0.f;
            #pragma unroll
            for (int jj = 0; jj < 8; ++jj) {
                float p = __expf(lrelu(si + sjv[jj]));
                f16 ph = (f16)p; lsum += (float)ph; ap[mt][0][jj] = ph;
                p = __expf(lrelu(si + sjv[8 + jj]));
                ph = (f16)p; lsum += (float)ph; ap[mt][1][jj] = ph;
            }
            lsum += __shfl_xor(lsum, 16, 64);
            lsum += __shfl_xor(lsum, 32, 64);
            inv1[mt] = 1.0f / lsum;        // row i = mt*16+lr (per-lane)
        }
    }

    // ---- product-1: PU^T = U^T @ P1^T  (D[c][i]) ----
    f16x8 af2[2];    // U^T A-frags: A[m=c][k=node], rows c=lr (only lr<3 valid)
    #pragma unroll
    for (int ks = 0; ks < 2; ++ks) {
        #pragma unroll
        for (int jj = 0; jj < 8; ++jj) {
            const int node = ks * 32 + lq * 8 + jj;
            af2[ks][jj] = (lr < 3) ? (f16)users[b * 192 + node * 3 + lr] : (f16)0.f;
        }
    }
    f32x4 d1[4];
    #pragma unroll
    for (int nt = 0; nt < 4; ++nt) {
        d1[nt] = (f32x4){0.f, 0.f, 0.f, 0.f};
        d1[nt] = __builtin_amdgcn_mfma_f32_16x16x32_f16(af2[0], ap[nt][0], d1[nt], 0, 0, 0);
        d1[nt] = __builtin_amdgcn_mfma_f32_16x16x32_f16(af2[1], ap[nt][1], d1[nt], 0, 0, 0);
    }
    // PU^T as B-frags: B[k=c][n=i_local]
    f16x8 bfr[4];
    #pragma unroll
    for (int nt = 0; nt < 4; ++nt) {
        const float c0 = __shfl(d1[nt][0], lr, 64);
        const float c1 = __shfl(d1[nt][1], lr, 64);
        const float c2 = __shfl(d1[nt][2], lr, 64);
        #pragma unroll
        for (int jj = 0; jj < 8; ++jj) bfr[nt][jj] = (f16)0.f;
        if (lq == 0) {
            bfr[nt][0] = (f16)c0; bfr[nt][1] = (f16)c1; bfr[nt][2] = (f16)c2;
        }
    }

    // ================= layer-1 halves: h1^T = W1^T @ PU^T -> bounce -> hf =========
    f16x8 hf[4][4];    // h1 as A-frags for F: [node-tile][k-frag]
    #pragma unroll
    for (int h = 0; h < 2; ++h) {
        __syncthreads();    // bounce region reuse across halves
        #pragma unroll
        for (int ftl = 0; ftl < 4; ++ftl) {
            f16x8 af3;      // W1^T A-frag: A[m=f][k=c], f = (h*4+ftl)*16+lr
            #pragma unroll
            for (int jj = 0; jj < 8; ++jj) af3[jj] = (f16)0.f;
            if (lq == 0) {
                #pragma unroll
                for (int jj = 0; jj < 3; ++jj)
                    af3[jj] = (f16)W1[jj * 128 + (h * 4 + ftl) * 16 + lr];
            }
            #pragma unroll
            for (int nt = 0; nt < 4; ++nt) {
                f32x4 acc = (f32x4){0.f, 0.f, 0.f, 0.f};
                acc = __builtin_amdgcn_mfma_f32_16x16x32_f16(af3, bfr[nt], acc, 0, 0, 0);
                f16x4 hv;
                #pragma unroll
                for (int r = 0; r < 4; ++r) hv[r] = (f16)elu1(acc[r] * inv1[nt]);
                const int n = nt * 16 + lr;
                const int g = 2 * ftl + (lq >> 1);
                *(f16x4*)&sMain[n * 64 + ((g ^ (n & 7)) << 3) + ((lq & 1) * 4)] = hv;
            }
        }
        __syncthreads();
        #pragma unroll
        for (int nt = 0; nt < 4; ++nt) {
            const int n = nt * 16 + lr;
            #pragma unroll
            for (int ksl = 0; ksl < 2; ++ksl)
                hf[nt][h * 2 + ksl] =
                    *(const f16x8*)&sMain[n * 64 + (((ksl * 4 + lq) ^ (n & 7)) << 3)];
        }
    }

    // ---- scores layer 2 via MFMA: D[m=node][n] = h1 @ [W2a2i | W2a2j] ----
    {
        f32x4 sacc[4];
        #pragma unroll
        for (int mt = 0; mt < 4; ++mt) sacc[mt] = (f32x4){0.f, 0.f, 0.f, 0.f};
        #pragma unroll
        for (int ks = 0; ks < 4; ++ks) {
            f16x8 bsw = *(const f16x8*)(w2ab + (ks * 64 + lane) * 8);
            #pragma unroll
            for (int mt = 0; mt < 4; ++mt)
                sacc[mt] = __builtin_amdgcn_mfma_f32_16x16x32_f16(hf[mt][ks], bsw, sacc[mt], 0, 0, 0);
        }
        if (lr < 2) {
            float* dst = (lr == 0) ? sSi : sSj;
            #pragma unroll
            for (int mt = 0; mt < 4; ++mt) {
                #pragma unroll
                for (int r = 0; r < 4; ++r)
                    dst[mt * 16 + lq * 4 + r] = sacc[mt][r];
            }
        }
        __syncthreads();   // also protects sMain (hf reads done) before F overwrites
    }

    // ================= F: FULL Wh2 = h1 @ W2 (both halves; hf's last use) =========
    #pragma unroll
    for (int h = 0; h < 2; ++h) {
        #pragma unroll
        for (int f2t = 0; f2t < 4; ++f2t) {
            f16x8 bw2[4];
            #pragma unroll
            for (int kf = 0; kf < 4; ++kf)
                bw2[kf] = *(const f16x8*)(w2b + (((h * 4 + f2t) * 4 + kf) * 64 + lane) * 8);
            #pragma unroll
            for (int ntile = 0; ntile < 4; ++ntile) {
                f32x4 acc = (f32x4){0.f, 0.f, 0.f, 0.f};
                #pragma unroll
                for (int kf = 0; kf < 4; ++kf)
                    acc = __builtin_amdgcn_mfma_f32_16x16x32_f16(hf[ntile][kf], bw2[kf], acc, 0, 0, 0);
                const int fl = h * 64 + f2t * 16 + lr;          // node = ntile*16+lq*4+r
                const int g = ntile * 2 + (lq >> 1);
                f16x4 hv;
                #pragma unroll
                for (int r = 0; r < 4; ++r) hv[r] = (f16)acc[r];
                *(f16x4*)&sMain[fl * 64 + ((g ^ (fl & 7)) << 3) + ((lq & 1) * 4)] = hv;
            }
        }
    }
    __syncthreads();

    // ================= E1: softmax-2 (built once; hf dead) + pool ================
    {
        f16x8 bp[4][2];
        float inv2[4];
        {
            float sjv[16];
            *(float4*)&sjv[0]  = *(const float4*)&sSj[lq * 8];
            *(float4*)&sjv[4]  = *(const float4*)&sSj[lq * 8 + 4];
            *(float4*)&sjv[8]  = *(const float4*)&sSj[32 + lq * 8];
            *(float4*)&sjv[12] = *(const float4*)&sSj[32 + lq * 8 + 4];
            #pragma unroll
            for (int mt = 0; mt < 4; ++mt) {
                const float si = sSi[mt * 16 + lr];
                float lsum = 0.f;
                #pragma unroll
                for (int jj = 0; jj < 8; ++jj) {
                    float p = __expf(lrelu(si + sjv[jj]));
                    f16 ph = (f16)p; lsum += (float)ph; bp[mt][0][jj] = ph;
                    p = __expf(lrelu(si + sjv[8 + jj]));
                    ph = (f16)p; lsum += (float)ph; bp[mt][1][jj] = ph;
                }
                lsum += __shfl_xor(lsum, 16, 64);
                lsum += __shfl_xor(lsum, 32, 64);
                inv2[mt] = 1.0f / lsum;
            }
        }

        #pragma unroll
        for (int ftl = 0; ftl < 8; ++ftl) {
            const int fl = ftl * 16 + lr;
            f16x8 b0 = *(const f16x8*)&sMain[fl * 64 + ((lq ^ (fl & 7)) << 3)];
            f16x8 b1 = *(const f16x8*)&sMain[fl * 64 + (((4 + lq) ^ (fl & 7)) << 3)];
            f32x4 mx4 = (f32x4){-1e30f, -1e30f, -1e30f, -1e30f};
            #pragma unroll
            for (int mt = 0; mt < 4; ++mt) {
                f32x4 acc = (f32x4){0.f, 0.f, 0.f, 0.f};
                acc = __builtin_amdgcn_mfma_f32_16x16x32_f16(b0, bp[mt][0], acc, 0, 0, 0);
                acc = __builtin_amdgcn_mfma_f32_16x16x32_f16(b1, bp[mt][1], acc, 0, 0, 0);
                #pragma unroll
                for (int r = 0; r < 4; ++r)
                    mx4[r] = fmaxf(mx4[r], acc[r] * inv2[mt]);
            }
            #pragma unroll
            for (int m = 1; m < 16; m <<= 1) {
                #pragma unroll
                for (int r = 0; r < 4; ++r)
                    mx4[r] = fmaxf(mx4[r], __shfl_xor(mx4[r], m, 64));
            }
            if (lr == 0) {
                float4 pv;
                pv.x = elu1(mx4[0]); pv.y = elu1(mx4[1]);
                pv.z = elu1(mx4[2]); pv.w = elu1(mx4[3]);
                *(float4*)&sPool[ftl * 16 + lq * 4] = pv;
            }
        }
    }
    __syncthreads();

    // ================= Readout (per-wave, fp32) =================
    {
        const int o = lane & 31, hh = lane >> 5;
        float s = 0.f;
        #pragma unroll 8
        for (int kk = 0; kk < 64; ++kk) {
            const int c = hh * 64 + kk;
            s = fmaf(sPool[c], mw1[c * 32 + o], s);
        }
        s += __shfl_xor(s, 32, 64);
        s = fmaxf(s + mb1[o], 0.0f);
        if (lane < 32) sHid[lane] = s;
    }
    __syncthreads();
    {
        float sA = mb2[lane], sB = mb2[64 + lane];
        #pragma unroll 8
        for (int q = 0; q < 32; ++q) {
            const float hq = sHid[q];
            sA = fmaf(hq, mw2[q * 128 + lane], sA);
            sB = fmaf(hq, mw2[q * 128 + 64 + lane], sB);
        }
        const float rA = fmaxf(sA, 0.0f) + 1e-6f;   // raw_delta[lane]
        const float rB = fmaxf(sB, 0.0f) + 1e-6f;   // raw_power[lane]
        float sumA = rA, sumB = rB;
        #pragma unroll
        for (int m = 1; m < 64; m <<= 1) {
            sumA += __shfl_xor(sumA, m, 64);
            sumB += __shfl_xor(sumB, m, 64);
        }
        out[b * 64 + lane]        = rB / (sumB + 1e-6f);            // power (PMAX = 1)
        out[OUT2 + b * 64 + lane] = 98.425f * rA / (sumA + 1e-6f);  // delta (Bmax = 98.425)
    }
}

extern "C" void kernel_launch(void* const* d_in, const int* in_sizes, int n_in,
                              void* d_out, int out_size, void* d_ws, size_t ws_size,
                              hipStream_t stream) {
    const float* users = (const float*)d_in[0];
    const float* W1    = (const float*)d_in[1];
    const float* a1    = (const float*)d_in[2];
    const float* W2    = (const float*)d_in[3];
    const float* a2    = (const float*)d_in[4];
    const float* mw1   = (const float*)d_in[5];
    const float* mb1   = (const float*)d_in[6];
    const float* mw2   = (const float*)d_in[7];
    const float* mb2   = (const float*)d_in[8];
    float* out = (float*)d_out;

    f16*   w2b  = (f16*)d_ws;
    float* w1a  = (float*)((char*)d_ws + 32768);
    f16*   w2ab = (f16*)((char*)d_ws + 32800);

    prep<<<64, 256, 0, stream>>>(W2, W1, a1, a2, w2b, w1a, w2ab);
    gat_kernel<<<NBATCH, 64, 0, stream>>>(users, W1, w2b, w1a, w2ab,
                                          mw1, mb1, mw2, mb2, out);
}

// Round 14
// 112.808 us; speedup vs baseline: 1.0772x; 1.0772x over previous
//
#include <hip/hip_runtime.h>

#define NBATCH 4096
#define OUT2 (NBATCH * 64)

typedef _Float16 f16;
typedef __attribute__((ext_vector_type(8))) _Float16 f16x8;
typedef __attribute__((ext_vector_type(4))) _Float16 f16x4;
typedef __attribute__((ext_vector_type(4))) float f32x4;

__device__ __forceinline__ float lrelu(float x) { return x > 0.0f ? x : 0.2f * x; }
__device__ __forceinline__ float elu1(float x)  { return x > 0.0f ? x : __expf(x) - 1.0f; }

// ---------------- prep ----------------
// ws: [0,32768)      w2b  f16 MFMA B-frags: w2b[((F2T*4+kf)*64+ln)*8+j] = W2[kf*32+(ln>>4)*8+j][F2T*16+(ln&15)]
//     [32768,32792)  w1a  f32[6] = {W1^T@a1[:128] (3), W1^T@a1[128:] (3)}
//     [32800,36896)  w2ab f16 B-frags of [W2@a2[:128] | W2@a2[128:]] (2 cols)
__global__ void prep(const float* __restrict__ W2, const float* __restrict__ W1,
                     const float* __restrict__ a1, const float* __restrict__ a2,
                     f16* __restrict__ w2b, float* __restrict__ w1a, f16* __restrict__ w2ab) {
    const int flat = blockIdx.x * 256 + threadIdx.x;   // 0..16383
    const int slot = flat >> 3, j = flat & 7;
    const int F2T = slot >> 8, kf = (slot >> 6) & 3, ln = slot & 63;
    const int lq = ln >> 4, lr = ln & 15;
    w2b[flat] = (f16)W2[(kf * 32 + lq * 8 + j) * 128 + F2T * 16 + lr];
    if (flat < 2048) {
        const int ks = flat >> 9, ln2 = (flat >> 3) & 63, jj = flat & 7;
        const int k = ks * 32 + ((ln2 >> 4) & 3) * 8 + jj;
        const int n = ln2 & 15;
        float v = 0.f;
        if (n < 2) {
            const float* av = a2 + n * 128;
            for (int f2 = 0; f2 < 128; ++f2) v = fmaf(W2[k * 128 + f2], av[f2], v);
        }
        w2ab[flat] = (f16)v;
    }
    if (flat >= 16381) {   // last 3 threads: w1a
        const int c = flat - 16381;
        float si = 0.f, sj = 0.f;
        for (int f = 0; f < 128; ++f) {
            const float w = W1[c * 128 + f];
            si = fmaf(w, a1[f], si);
            sj = fmaf(w, a1[128 + f], sj);
        }
        w1a[c] = si; w1a[3 + c] = sj;
    }
}

// One wave = TWO batches (ILP-2). sMain 16 KB:
//  - layer-1 bounces: batch g at g*4096 + n*64 + (((fl>>3)^(n&7))<<3) + (fl&7)   (8 KB each)
//  - F/E1 per batch : full Wh2 [f 0..127][n] : f*64 + (((n>>3)^(f&7))<<3) + (n&7)
__global__ __launch_bounds__(64, 2)
void gat_kernel(const float* __restrict__ users,
                const float* __restrict__ W1,
                const f16* __restrict__ w2b,
                const float* __restrict__ w1a,
                const f16* __restrict__ w2ab,
                const float* __restrict__ mw1,
                const float* __restrict__ mb1,
                const float* __restrict__ mw2,
                const float* __restrict__ mb2,
                float* __restrict__ out)
{
    const int b0 = blockIdx.x * 2;
    const int lane = threadIdx.x;
    const int lr = lane & 15;
    const int lq = lane >> 4;

    __shared__ __align__(16) char smem[18688];
    f16*   sMain = (f16*)smem;                   // 16384 B
    float* sSiA  = (float*)(smem + 16384);       // [2][64]
    float* sSjA  = (float*)(smem + 16896);       // [2][64]
    float* sPoolA= (float*)(smem + 17408);       // [2][128]
    float* sHidA = (float*)(smem + 18432);       // [2][32]

    // ---- scores layer 1 (both batches): rank-3 exact fp32 ----
    #pragma unroll
    for (int g = 0; g < 2; ++g) {
        const float* u = users + (b0 + g) * 192;
        const float x = u[lane * 3], y = u[lane * 3 + 1], z = u[lane * 3 + 2];
        sSiA[g * 64 + lane] = fmaf(x, w1a[0], fmaf(y, w1a[1], z * w1a[2]));
        sSjA[g * 64 + lane] = fmaf(x, w1a[3], fmaf(y, w1a[4], z * w1a[5]));
    }
    __syncthreads();

    // ---- softmax-1 + product-1 + PU^T B-frags, per batch ----
    f16x8 bfr[2][4];     // PU^T as B-frags  (32 VGPRs)
    float inv1[2][4];
    #pragma unroll
    for (int g = 0; g < 2; ++g) {
        const float* sSi = sSiA + g * 64;
        const float* sSj = sSjA + g * 64;
        float sjv[16];
        *(float4*)&sjv[0]  = *(const float4*)&sSj[lq * 8];
        *(float4*)&sjv[4]  = *(const float4*)&sSj[lq * 8 + 4];
        *(float4*)&sjv[8]  = *(const float4*)&sSj[32 + lq * 8];
        *(float4*)&sjv[12] = *(const float4*)&sSj[32 + lq * 8 + 4];
        f16x8 ap[4][2];
        #pragma unroll
        for (int mt = 0; mt < 4; ++mt) {
            const float si = sSi[mt * 16 + lr];
            float lsum = 0.f;
            #pragma unroll
            for (int jj = 0; jj < 8; ++jj) {
                float p = __expf(lrelu(si + sjv[jj]));
                f16 ph = (f16)p; lsum += (float)ph; ap[mt][0][jj] = ph;
                p = __expf(lrelu(si + sjv[8 + jj]));
                ph = (f16)p; lsum += (float)ph; ap[mt][1][jj] = ph;
            }
            lsum += __shfl_xor(lsum, 16, 64);
            lsum += __shfl_xor(lsum, 32, 64);
            inv1[g][mt] = 1.0f / lsum;
        }
        // product-1: PU^T = U^T @ P1^T
        f16x8 af2[2];
        #pragma unroll
        for (int ks = 0; ks < 2; ++ks) {
            #pragma unroll
            for (int jj = 0; jj < 8; ++jj) {
                const int node = ks * 32 + lq * 8 + jj;
                af2[ks][jj] = (lr < 3) ? (f16)users[(b0 + g) * 192 + node * 3 + lr] : (f16)0.f;
            }
        }
        #pragma unroll
        for (int nt = 0; nt < 4; ++nt) {
            f32x4 d1 = (f32x4){0.f, 0.f, 0.f, 0.f};
            d1 = __builtin_amdgcn_mfma_f32_16x16x32_f16(af2[0], ap[nt][0], d1, 0, 0, 0);
            d1 = __builtin_amdgcn_mfma_f32_16x16x32_f16(af2[1], ap[nt][1], d1, 0, 0, 0);
            const float c0 = __shfl(d1[0], lr, 64);
            const float c1 = __shfl(d1[1], lr, 64);
            const float c2 = __shfl(d1[2], lr, 64);
            #pragma unroll
            for (int jj = 0; jj < 8; ++jj) bfr[g][nt][jj] = (f16)0.f;
            if (lq == 0) {
                bfr[g][nt][0] = (f16)c0; bfr[g][nt][1] = (f16)c1; bfr[g][nt][2] = (f16)c2;
            }
        }
    }

    // ================= layer-1 halves: h1^T = W1^T @ PU^T, both batches ==========
    f16x8 hf[2][4][4];   // 128 VGPRs: h1 A-frags for both batches
    #pragma unroll
    for (int h = 0; h < 2; ++h) {
        __syncthreads();    // bounce region reuse across halves
        #pragma unroll
        for (int ftl = 0; ftl < 4; ++ftl) {
            f16x8 af3;      // W1^T A-frag — SHARED by both batches
            #pragma unroll
            for (int jj = 0; jj < 8; ++jj) af3[jj] = (f16)0.f;
            if (lq == 0) {
                #pragma unroll
                for (int jj = 0; jj < 3; ++jj)
                    af3[jj] = (f16)W1[jj * 128 + (h * 4 + ftl) * 16 + lr];
            }
            #pragma unroll
            for (int g = 0; g < 2; ++g) {
                #pragma unroll
                for (int nt = 0; nt < 4; ++nt) {
                    f32x4 acc = (f32x4){0.f, 0.f, 0.f, 0.f};
                    acc = __builtin_amdgcn_mfma_f32_16x16x32_f16(af3, bfr[g][nt], acc, 0, 0, 0);
                    f16x4 hv;
                    #pragma unroll
                    for (int r = 0; r < 4; ++r) hv[r] = (f16)elu1(acc[r] * inv1[g][nt]);
                    const int n = nt * 16 + lr;
                    const int gg = 2 * ftl + (lq >> 1);
                    *(f16x4*)&sMain[g * 4096 + n * 64 + ((gg ^ (n & 7)) << 3) + ((lq & 1) * 4)] = hv;
                }
            }
        }
        __syncthreads();
        #pragma unroll
        for (int g = 0; g < 2; ++g) {
            #pragma unroll
            for (int nt = 0; nt < 4; ++nt) {
                const int n = nt * 16 + lr;
                #pragma unroll
                for (int ksl = 0; ksl < 2; ++ksl)
                    hf[g][nt][h * 2 + ksl] =
                        *(const f16x8*)&sMain[g * 4096 + n * 64 + (((ksl * 4 + lq) ^ (n & 7)) << 3)];
            }
        }
    }

    // ---- scores layer 2 via MFMA (w2ab frags shared by both batches) ----
    {
        f32x4 sacc[2][4];
        #pragma unroll
        for (int g = 0; g < 2; ++g)
            #pragma unroll
            for (int mt = 0; mt < 4; ++mt) sacc[g][mt] = (f32x4){0.f, 0.f, 0.f, 0.f};
        #pragma unroll
        for (int ks = 0; ks < 4; ++ks) {
            f16x8 bsw = *(const f16x8*)(w2ab + (ks * 64 + lane) * 8);
            #pragma unroll
            for (int g = 0; g < 2; ++g)
                #pragma unroll
                for (int mt = 0; mt < 4; ++mt)
                    sacc[g][mt] = __builtin_amdgcn_mfma_f32_16x16x32_f16(hf[g][mt][ks], bsw, sacc[g][mt], 0, 0, 0);
        }
        if (lr < 2) {
            #pragma unroll
            for (int g = 0; g < 2; ++g) {
                float* dst = (lr == 0) ? (sSiA + g * 64) : (sSjA + g * 64);
                #pragma unroll
                for (int mt = 0; mt < 4; ++mt)
                    #pragma unroll
                    for (int r = 0; r < 4; ++r)
                        dst[mt * 16 + lq * 4 + r] = sacc[g][mt][r];
            }
        }
    }

    // ================= F + E1, per batch (sMain reused serially) =================
    #pragma unroll
    for (int g = 0; g < 2; ++g) {
        __syncthreads();   // g=0: hf loads + score stores done; g=1: E1(0) reads done
        // F(g): full Wh2 = h1 @ W2  (bw2 loads per g — L1-resident)
        #pragma unroll
        for (int h = 0; h < 2; ++h) {
            #pragma unroll
            for (int f2t = 0; f2t < 4; ++f2t) {
                f16x8 bw2[4];
                #pragma unroll
                for (int kf = 0; kf < 4; ++kf)
                    bw2[kf] = *(const f16x8*)(w2b + (((h * 4 + f2t) * 4 + kf) * 64 + lane) * 8);
                #pragma unroll
                for (int ntile = 0; ntile < 4; ++ntile) {
                    f32x4 acc = (f32x4){0.f, 0.f, 0.f, 0.f};
                    #pragma unroll
                    for (int kf = 0; kf < 4; ++kf)
                        acc = __builtin_amdgcn_mfma_f32_16x16x32_f16(hf[g][ntile][kf], bw2[kf], acc, 0, 0, 0);
                    const int fl = h * 64 + f2t * 16 + lr;
                    const int gg = ntile * 2 + (lq >> 1);
                    f16x4 hv;
                    #pragma unroll
                    for (int r = 0; r < 4; ++r) hv[r] = (f16)acc[r];
                    *(f16x4*)&sMain[fl * 64 + ((gg ^ (fl & 7)) << 3) + ((lq & 1) * 4)] = hv;
                }
            }
        }
        __syncthreads();

        // E1(g): softmax-2 built once; pool
        const float* sSi = sSiA + g * 64;
        const float* sSj = sSjA + g * 64;
        f16x8 bp[4][2];
        float inv2[4];
        {
            float sjv[16];
            *(float4*)&sjv[0]  = *(const float4*)&sSj[lq * 8];
            *(float4*)&sjv[4]  = *(const float4*)&sSj[lq * 8 + 4];
            *(float4*)&sjv[8]  = *(const float4*)&sSj[32 + lq * 8];
            *(float4*)&sjv[12] = *(const float4*)&sSj[32 + lq * 8 + 4];
            #pragma unroll
            for (int mt = 0; mt < 4; ++mt) {
                const float si = sSi[mt * 16 + lr];
                float lsum = 0.f;
                #pragma unroll
                for (int jj = 0; jj < 8; ++jj) {
                    float p = __expf(lrelu(si + sjv[jj]));
                    f16 ph = (f16)p; lsum += (float)ph; bp[mt][0][jj] = ph;
                    p = __expf(lrelu(si + sjv[8 + jj]));
                    ph = (f16)p; lsum += (float)ph; bp[mt][1][jj] = ph;
                }
                lsum += __shfl_xor(lsum, 16, 64);
                lsum += __shfl_xor(lsum, 32, 64);
                inv2[mt] = 1.0f / lsum;
            }
        }
        #pragma unroll
        for (int ftl = 0; ftl < 8; ++ftl) {
            const int fl = ftl * 16 + lr;
            f16x8 bh0 = *(const f16x8*)&sMain[fl * 64 + ((lq ^ (fl & 7)) << 3)];
            f16x8 bh1 = *(const f16x8*)&sMain[fl * 64 + (((4 + lq) ^ (fl & 7)) << 3)];
            f32x4 mx4 = (f32x4){-1e30f, -1e30f, -1e30f, -1e30f};
            #pragma unroll
            for (int mt = 0; mt < 4; ++mt) {
                f32x4 acc = (f32x4){0.f, 0.f, 0.f, 0.f};
                acc = __builtin_amdgcn_mfma_f32_16x16x32_f16(bh0, bp[mt][0], acc, 0, 0, 0);
                acc = __builtin_amdgcn_mfma_f32_16x16x32_f16(bh1, bp[mt][1], acc, 0, 0, 0);
                #pragma unroll
                for (int r = 0; r < 4; ++r)
                    mx4[r] = fmaxf(mx4[r], acc[r] * inv2[mt]);
            }
            #pragma unroll
            for (int m = 1; m < 16; m <<= 1) {
                #pragma unroll
                for (int r = 0; r < 4; ++r)
                    mx4[r] = fmaxf(mx4[r], __shfl_xor(mx4[r], m, 64));
            }
            if (lr == 0) {
                float4 pv;
                pv.x = elu1(mx4[0]); pv.y = elu1(mx4[1]);
                pv.z = elu1(mx4[2]); pv.w = elu1(mx4[3]);
                *(float4*)&sPoolA[g * 128 + ftl * 16 + lq * 4] = pv;
            }
        }
    }
    __syncthreads();

    // ================= Readout (both batches; weight loads shared) ===============
    {
        const int o = lane & 31, hh = lane >> 5;
        float s0 = 0.f, s1 = 0.f;
        #pragma unroll 8
        for (int kk = 0; kk < 64; ++kk) {
            const int c = hh * 64 + kk;
            const float w = mw1[c * 32 + o];
            s0 = fmaf(sPoolA[c], w, s0);
            s1 = fmaf(sPoolA[128 + c], w, s1);
        }
        s0 += __shfl_xor(s0, 32, 64);
        s1 += __shfl_xor(s1, 32, 64);
        const float bb = mb1[o];
        if (lane < 32) {
            sHidA[lane] = fmaxf(s0 + bb, 0.0f);
            sHidA[32 + lane] = fmaxf(s1 + bb, 0.0f);
        }
    }
    __syncthreads();
    {
        const float mbA = mb2[lane], mbB = mb2[64 + lane];
        float sA0 = mbA, sB0 = mbB, sA1 = mbA, sB1 = mbB;
        #pragma unroll 8
        for (int q = 0; q < 32; ++q) {
            const float wA = mw2[q * 128 + lane];
            const float wB = mw2[q * 128 + 64 + lane];
            const float h0 = sHidA[q], h1 = sHidA[32 + q];
            sA0 = fmaf(h0, wA, sA0);  sB0 = fmaf(h0, wB, sB0);
            sA1 = fmaf(h1, wA, sA1);  sB1 = fmaf(h1, wB, sB1);
        }
        float rA0 = fmaxf(sA0, 0.0f) + 1e-6f, rB0 = fmaxf(sB0, 0.0f) + 1e-6f;
        float rA1 = fmaxf(sA1, 0.0f) + 1e-6f, rB1 = fmaxf(sB1, 0.0f) + 1e-6f;
        float uA0 = rA0, uB0 = rB0, uA1 = rA1, uB1 = rB1;
        #pragma unroll
        for (int m = 1; m < 64; m <<= 1) {
            uA0 += __shfl_xor(uA0, m, 64);  uB0 += __shfl_xor(uB0, m, 64);
            uA1 += __shfl_xor(uA1, m, 64);  uB1 += __shfl_xor(uB1, m, 64);
        }
        out[b0 * 64 + lane]              = rB0 / (uB0 + 1e-6f);
        out[OUT2 + b0 * 64 + lane]       = 98.425f * rA0 / (uA0 + 1e-6f);
        out[(b0 + 1) * 64 + lane]        = rB1 / (uB1 + 1e-6f);
        out[OUT2 + (b0 + 1) * 64 + lane] = 98.425f * rA1 / (uA1 + 1e-6f);
    }
}

extern "C" void kernel_launch(void* const* d_in, const int* in_sizes, int n_in,
                              void* d_out, int out_size, void* d_ws, size_t ws_size,
                              hipStream_t stream) {
    const float* users = (const float*)d_in[0];
    const float* W1    = (const float*)d_in[1];
    const float* a1    = (const float*)d_in[2];
    const float* W2    = (const float*)d_in[3];
    const float* a2    = (const float*)d_in[4];
    const float* mw1   = (const float*)d_in[5];
    const float* mb1   = (const float*)d_in[6];
    const float* mw2   = (const float*)d_in[7];
    const float* mb2   = (const float*)d_in[8];
    float* out = (float*)d_out;

    f16*   w2b  = (f16*)d_ws;
    float* w1a  = (float*)((char*)d_ws + 32768);
    f16*   w2ab = (f16*)((char*)d_ws + 32800);

    prep<<<64, 256, 0, stream>>>(W2, W1, a1, a2, w2b, w1a, w2ab);
    gat_kernel<<<NBATCH / 2, 64, 0, stream>>>(users, W1, w2b, w1a, w2ab,
                                              mw1, mb1, mw2, mb2, out);
}